// Round 1
// baseline (511.215 us; speedup 1.0000x reference)
//
#include <hip/hip_runtime.h>
#include <hip/hip_bf16.h>

typedef __attribute__((ext_vector_type(8))) short short8;
typedef __attribute__((ext_vector_type(4))) float f32x4;
typedef unsigned short u16;

#define DEVI static __device__ __forceinline__

constexpr int kB = 4;
constexpr int kN = 16384;
constexpr int kD = 256;
constexpr int kH = 2;
constexpr int kC = 128;

// ---------------- workspace layout (bytes) ----------------
constexpr size_t SZ_T16 = (size_t)kB * kD * kN * 2;   // one bf16 [4][256][16384] buffer
constexpr size_t O_Yt   = 0;                          // bf16 [4][256][16384]  LN(S) transposed
constexpr size_t O_Xt   = O_Yt + SZ_T16;              // bf16 [4][256][16384]  LN(R) transposed
constexpr size_t O_Xrow = O_Xt + SZ_T16;              // bf16 [4][16384][256]  LN(R) row-major
constexpr size_t SZ_G   = (size_t)3 * kB * kD * kD * 4;
constexpr size_t O_G    = O_Xrow + SZ_T16;            // f32 [3][4][256][256]  Gyx,Gyy,Gxx
constexpr size_t O_ysum = O_G + SZ_G;                 // f32 [4][256]
constexpr size_t O_xsum = O_ysum + (size_t)kB * kD * 4;
constexpr size_t O_T    = O_xsum + (size_t)kB * kD * 4; // f32 [3][4][256][256] T1,T2,T3
constexpr size_t O_qy   = O_T + SZ_G;                 // f32 [4][256]
constexpr size_t O_kq   = O_qy + (size_t)kB * kD * 4;
constexpr size_t O_nq2  = O_kq + (size_t)kB * kD * 4;
constexpr size_t O_nk2  = O_nq2 + (size_t)kB * kD * 4;
constexpr size_t O_A    = O_nk2 + (size_t)kB * kD * 4; // f32 [4][2][128][128]
constexpr size_t SZ_A   = (size_t)kB * kH * kC * kC * 4;
constexpr size_t O_W3   = O_A + SZ_A;                 // bf16 [4][256][256]
constexpr size_t O_b3   = O_W3 + (size_t)kB * kD * kD * 2; // f32 [4][256]
constexpr size_t WS_NEED = O_b3 + (size_t)kB * kD * 4;    // ~109 MB

DEVI u16 f2bf(float x) {
    unsigned u = __builtin_bit_cast(unsigned, x);
    unsigned r = (u + 0x7FFFu + ((u >> 16) & 1u)) >> 16;
    return (u16)r;
}

// ---------------- 1) LayerNorm: f32 [b][n][256] -> bf16 transposed [b][256][n]
//                    (+ optional row-major bf16 copy, + per-(b,col) sums) ------
__global__ __launch_bounds__(256) void ln_kernel(
    const float* __restrict__ x, const float* __restrict__ w, const float* __restrict__ bia,
    u16* __restrict__ outT, u16* __restrict__ outR, float* __restrict__ colsum)
{
    constexpr int ROWS = 32;
    __shared__ u16 tile[256][36];     // stride 36 u16 = 72B (bank decorrelation)
    __shared__ float csum[4][256];
    int blk = blockIdx.x;
    int b = blk >> 9;                 // 512 blocks per b
    int n0 = (blk & 511) * ROWS;
    int lane = threadIdx.x & 63, wave = threadIdx.x >> 6;

    float wv[4], bv[4];
#pragma unroll
    for (int j = 0; j < 4; j++) { int c = lane + 64 * j; wv[j] = w[c]; bv[j] = bia[c]; }
    float acc[4] = {0.f, 0.f, 0.f, 0.f};

    for (int i = 0; i < 8; i++) {
        int r = wave * 8 + i;
        const float* xp = x + ((size_t)(b * kN + n0 + r)) * kD;
        float v[4];
#pragma unroll
        for (int j = 0; j < 4; j++) v[j] = xp[lane + 64 * j];
        float s  = v[0] + v[1] + v[2] + v[3];
        float sq = v[0]*v[0] + v[1]*v[1] + v[2]*v[2] + v[3]*v[3];
#pragma unroll
        for (int off = 32; off; off >>= 1) { s += __shfl_xor(s, off); sq += __shfl_xor(sq, off); }
        float mean = s * (1.f / kD);
        float var  = sq * (1.f / kD) - mean * mean;   // biased, matches jnp.var
        float rstd = rsqrtf(var + 1e-5f);
#pragma unroll
        for (int j = 0; j < 4; j++) {
            float y = (v[j] - mean) * rstd * wv[j] + bv[j];
            acc[j] += y;
            u16 u = f2bf(y);
            tile[lane + 64 * j][r] = u;
            if (outR) outR[((size_t)(b * kN + n0 + r)) * kD + lane + 64 * j] = u;
        }
    }
#pragma unroll
    for (int j = 0; j < 4; j++) csum[wave][lane + 64 * j] = acc[j];
    __syncthreads();
    int t = threadIdx.x;
    unsafeAtomicAdd(&colsum[b * kD + t], csum[0][t] + csum[1][t] + csum[2][t] + csum[3][t]);

    // transposed write-out: each (c) row emits 32 contiguous n as 2x16B
#pragma unroll
    for (int pass = 0; pass < 2; pass++) {
        int c = pass * 128 + (t >> 1);
        int q = t & 1;
        const u16* src = &tile[c][q * 16];
        uint2 p0 = *(const uint2*)(src + 0);
        uint2 p1 = *(const uint2*)(src + 4);
        uint2 p2 = *(const uint2*)(src + 8);
        uint2 p3 = *(const uint2*)(src + 12);
        u16* dst = outT + ((size_t)(b * kD + c)) * kN + n0 + q * 16;
        *(uint4*)(dst)     = make_uint4(p0.x, p0.y, p1.x, p1.y);
        *(uint4*)(dst + 8) = make_uint4(p2.x, p2.y, p3.x, p3.y);
    }
}

// ---------------- 2) Gram kernel: G[w][b] += A_chunk^T * B_chunk (bf16 MFMA, split-K atomics)
__global__ __launch_bounds__(256) void gram_kernel(
    const u16* __restrict__ Yt, const u16* __restrict__ Xt, float* __restrict__ G)
{
    int id = blockIdx.x;            // 4b * 16chunk * 3which * 4tile = 768
    int b = id / 192;
    int r = id % 192;
    int chunk = r / 12;
    int r2 = r % 12;
    int which = r2 >> 2;            // 0:Gyx 1:Gyy 2:Gxx
    int tm = (r2 >> 1) & 1, tn = r2 & 1;
    const u16* Ap = (which == 2) ? Xt : Yt;
    const u16* Bp = (which == 1) ? Yt : Xt;

    int lane = threadIdx.x & 63, wave = threadIdx.x >> 6;
    int wr = wave >> 1, wc = wave & 1;
    int m0 = tm * 128 + wr * 64, j0 = tn * 128 + wc * 64;
    int li = lane & 15, klo = lane >> 4;
    size_t nbase = (size_t)chunk * 1024 + klo * 8;

    const short8* arow[4];
    const short8* brow[4];
#pragma unroll
    for (int f = 0; f < 4; f++) {
        arow[f] = (const short8*)(Ap + ((size_t)(b * kD + m0 + f * 16 + li)) * kN + nbase);
        brow[f] = (const short8*)(Bp + ((size_t)(b * kD + j0 + f * 16 + li)) * kN + nbase);
    }

    f32x4 acc[4][4] = {};
    for (int ks = 0; ks < 32; ks++) {            // 1024 n per chunk, 32 per step
        short8 a[4], bb[4];
#pragma unroll
        for (int f = 0; f < 4; f++) a[f]  = arow[f][ks * 4];
#pragma unroll
        for (int f = 0; f < 4; f++) bb[f] = brow[f][ks * 4];
#pragma unroll
        for (int fi = 0; fi < 4; fi++)
#pragma unroll
            for (int fj = 0; fj < 4; fj++)
                acc[fi][fj] = __builtin_amdgcn_mfma_f32_16x16x32_bf16(a[fi], bb[fj], acc[fi][fj], 0, 0, 0);
    }

    float* Gb = G + ((size_t)(which * 4 + b)) * (kD * kD);
#pragma unroll
    for (int fi = 0; fi < 4; fi++) {
        int row = m0 + fi * 16 + klo * 4;
#pragma unroll
        for (int fj = 0; fj < 4; fj++) {
            int col = j0 + fj * 16 + li;
#pragma unroll
            for (int rr = 0; rr < 4; rr++)
                unsafeAtomicAdd(&Gb[(size_t)(row + rr) * kD + col], acc[fi][fj][rr]);
        }
    }
}

// ---------------- 3) T{1,2,3}[w][b] = Wrow * G[w][b] ----------------
__global__ __launch_bounds__(256) void tmul_kernel(
    const float* __restrict__ G, const float* __restrict__ Wq, const float* __restrict__ Wkv,
    float* __restrict__ T)
{
    int id = blockIdx.x;            // 3*4*32 = 384
    int otile = id & 31; id >>= 5;
    int b = id & 3;      id >>= 2;
    int which = id;                  // 0:Wq*Gyx 1:Wq*Gyy 2:Wk*Gxx
    const float* W  = (which == 2) ? Wkv : Wq;
    const float* Gb = G + ((size_t)(which * 4 + b)) * (kD * kD);
    float* Tb       = T + ((size_t)(which * 4 + b)) * (kD * kD);
    int d = threadIdx.x;
    int o0 = otile * 8;
    float acc[8] = {};
    for (int m = 0; m < 256; m++) {
        float g = Gb[(size_t)m * kD + d];
#pragma unroll
        for (int oo = 0; oo < 8; oo++) acc[oo] = fmaf(W[(o0 + oo) * kD + m], g, acc[oo]);
    }
#pragma unroll
    for (int oo = 0; oo < 8; oo++) Tb[(size_t)(o0 + oo) * kD + d] = acc[oo];
}

// ---------------- 4) per-channel scalars: qy,kq,|q|^2,|k|^2 ----------------
__global__ __launch_bounds__(256) void vec_kernel(
    const float* __restrict__ T, const float* __restrict__ Wq, const float* __restrict__ Wkv,
    const float* __restrict__ bq, const float* __restrict__ bkv,
    const float* __restrict__ ysum, const float* __restrict__ xsum,
    float* __restrict__ qy, float* __restrict__ kq,
    float* __restrict__ nq2, float* __restrict__ nk2)
{
    __shared__ float ys[256], xs[256];
    int b = blockIdx.x, e = threadIdx.x;
    ys[e] = ysum[b * kD + e];
    xs[e] = xsum[b * kD + e];
    __syncthreads();
    const float* T2  = T + ((size_t)(1 * 4 + b)) * (kD * kD) + (size_t)e * kD;
    const float* T3  = T + ((size_t)(2 * 4 + b)) * (kD * kD) + (size_t)e * kD;
    const float* wqr = Wq + (size_t)e * kD;
    const float* wkr = Wkv + (size_t)e * kD;
    float dqy = 0, dkq = 0, d2 = 0, d3 = 0;
    for (int m = 0; m < 256; m++) {
        float a = wqr[m], c = wkr[m];
        dqy = fmaf(a, ys[m], dqy);
        dkq = fmaf(c, xs[m], dkq);
        d2  = fmaf(T2[m], a, d2);
        d3  = fmaf(T3[m], c, d3);
    }
    float bqe = bq[e], bke = bkv[e];
    qy[b * kD + e] = dqy;
    kq[b * kD + e] = dkq;
    nq2[b * kD + e] = d2 + 2.f * bqe * dqy + (float)kN * bqe * bqe;
    nk2[b * kD + e] = d3 + 2.f * bke * dkq + (float)kN * bke * bke;
}

// ---------------- 5) logits + softmax -> A[b][h][c][d] ----------------
__global__ __launch_bounds__(128) void attn_kernel(
    const float* __restrict__ T, const float* __restrict__ Wkv,
    const float* __restrict__ bq, const float* __restrict__ bkv,
    const float* __restrict__ qy, const float* __restrict__ kq,
    const float* __restrict__ nq2, const float* __restrict__ nk2,
    const float* __restrict__ temperature, float* __restrict__ A)
{
    __shared__ float t1[256];
    __shared__ float red[4];
    int id = blockIdx.x;            // 4*2*128 = 1024, c fastest
    int c = id & 127; id >>= 7;
    int h = id & 1;
    int b = id >> 1;
    int e = h * 128 + c;
    int d = threadIdx.x;

    const float* T1 = T + ((size_t)(0 * 4 + b)) * (kD * kD) + (size_t)e * kD;
    t1[d] = T1[d];
    t1[128 + d] = T1[128 + d];
    __syncthreads();

    int f = h * 128 + d;
    const float* wkr = Wkv + (size_t)f * kD;
    float acc = 0;
    for (int m = 0; m < 256; m++) acc = fmaf(t1[m], wkr[m], acc);

    float bqe = bq[e], bkf = bkv[f];
    float graw = acc + bqe * kq[b * kD + f] + bkf * qy[b * kD + e] + (float)kN * bqe * bkf;
    float rq = 1.f / fmaxf(sqrtf(fmaxf(nq2[b * kD + e], 0.f)), 1e-12f);
    float rk = 1.f / fmaxf(sqrtf(fmaxf(nk2[b * kD + f], 0.f)), 1e-12f);
    float logit = graw * rq * rk * temperature[h];

    float mx = logit;
#pragma unroll
    for (int off = 32; off; off >>= 1) mx = fmaxf(mx, __shfl_xor(mx, off));
    int wv = d >> 6;
    if ((d & 63) == 0) red[wv] = mx;
    __syncthreads();
    mx = fmaxf(red[0], red[1]);
    float p = __expf(logit - mx);
    float sm = p;
#pragma unroll
    for (int off = 32; off; off >>= 1) sm += __shfl_xor(sm, off);
    if ((d & 63) == 0) red[2 + wv] = sm;
    __syncthreads();
    sm = red[2] + red[3];
    A[((size_t)((b * 2 + h) * kC + c)) * kC + d] = p / sm;
}

// ---------------- 6) fold Wo * blockdiag(A) * Wv -> W3[b] (bf16), b3[b] ----------------
__global__ __launch_bounds__(256) void mmat_kernel(
    const float* __restrict__ A, const float* __restrict__ Wo,
    const float* __restrict__ Wkv, const float* __restrict__ bkv,
    const float* __restrict__ bo, u16* __restrict__ W3, float* __restrict__ b3)
{
    __shared__ float Ml[256];
    int id = blockIdx.x;            // 4*256 = 1024
    int o = id & 255;
    int b = id >> 8;
    int t = threadIdx.x;
    int h = t >> 7, d = t & 127;

    const float* Ab  = A + ((size_t)(b * 2 + h)) * (kC * kC);
    const float* wor = Wo + (size_t)o * kD + h * 128;
    float acc = 0;
    for (int c2 = 0; c2 < 128; c2++) acc = fmaf(wor[c2], Ab[(size_t)c2 * kC + d], acc);
    Ml[t] = acc;
    __syncthreads();

    const float* wvp = Wkv + (size_t)256 * kD;   // rows 256..511 = Wv
    float w3 = 0, bsum = 0;
    for (int e2 = 0; e2 < 256; e2++) {
        float m = Ml[e2];
        w3   = fmaf(m, wvp[(size_t)e2 * kD + t], w3);
        bsum = fmaf(m, bkv[256 + e2], bsum);
    }
    W3[((size_t)(b * kD + o)) * kD + t] = f2bf(w3);
    if (t == 0) b3[b * kD + o] = bsum + bo[o];
}

// ---------------- 7) out[b][n][o] = Xrow[b][n][:] . W3[b][o][:] + b3[b][o] ----------------
__global__ __launch_bounds__(256) void outgemm_kernel(
    const u16* __restrict__ Xrow, const u16* __restrict__ W3,
    const float* __restrict__ b3, float* __restrict__ out)
{
    int id = blockIdx.x;            // 4b * 128mtile * 4ntile = 2048
    int ntile = id & 3;  id >>= 2;
    int mtile = id & 127; id >>= 7;
    int b = id;
    int lane = threadIdx.x & 63, wave = threadIdx.x >> 6;
    int li = lane & 15, klo = lane >> 4;
    int n0 = mtile * 128 + wave * 32;
    int o0 = ntile * 64;

    const short8* ar[2];
    const short8* br[4];
#pragma unroll
    for (int f = 0; f < 2; f++)
        ar[f] = (const short8*)(Xrow + ((size_t)(b * kN + n0 + f * 16 + li)) * kD + klo * 8);
#pragma unroll
    for (int f = 0; f < 4; f++)
        br[f] = (const short8*)(W3 + ((size_t)(b * kD + o0 + f * 16 + li)) * kD + klo * 8);

    f32x4 acc[2][4] = {};
#pragma unroll
    for (int ks = 0; ks < 8; ks++) {
        short8 a[2], bb[4];
#pragma unroll
        for (int f = 0; f < 2; f++) a[f]  = ar[f][ks * 4];
#pragma unroll
        for (int f = 0; f < 4; f++) bb[f] = br[f][ks * 4];
#pragma unroll
        for (int fi = 0; fi < 2; fi++)
#pragma unroll
            for (int fj = 0; fj < 4; fj++)
                acc[fi][fj] = __builtin_amdgcn_mfma_f32_16x16x32_bf16(a[fi], bb[fj], acc[fi][fj], 0, 0, 0);
    }

#pragma unroll
    for (int fj = 0; fj < 4; fj++) {
        float bias = b3[b * kD + o0 + fj * 16 + li];
#pragma unroll
        for (int fi = 0; fi < 2; fi++) {
            int nr = n0 + fi * 16 + klo * 4;
#pragma unroll
            for (int rr = 0; rr < 4; rr++)
                out[((size_t)(b * kN + nr + rr)) * kD + o0 + fj * 16 + li] = acc[fi][fj][rr] + bias;
        }
    }
}

// ---------------- launch ----------------
extern "C" void kernel_launch(void* const* d_in, const int* in_sizes, int n_in,
                              void* d_out, int out_size, void* d_ws, size_t ws_size,
                              hipStream_t stream)
{
    const float* input_R = (const float*)d_in[0];
    const float* input_S = (const float*)d_in[1];
    const float* lnS_w   = (const float*)d_in[2];
    const float* lnS_b   = (const float*)d_in[3];
    const float* lnR_w   = (const float*)d_in[4];
    const float* lnR_b   = (const float*)d_in[5];
    const float* Wq      = (const float*)d_in[6];
    const float* bq      = (const float*)d_in[7];
    const float* Wkv     = (const float*)d_in[8];
    const float* bkv     = (const float*)d_in[9];
    const float* Wo      = (const float*)d_in[10];
    const float* bo      = (const float*)d_in[11];
    const float* temp    = (const float*)d_in[12];
    float* out = (float*)d_out;
    char* ws = (char*)d_ws;

    u16*   Yt   = (u16*)(ws + O_Yt);
    u16*   Xt   = (u16*)(ws + O_Xt);
    u16*   Xrow = (u16*)(ws + O_Xrow);
    float* G    = (float*)(ws + O_G);
    float* ysum = (float*)(ws + O_ysum);
    float* xsum = (float*)(ws + O_xsum);
    float* T    = (float*)(ws + O_T);
    float* qy   = (float*)(ws + O_qy);
    float* kq   = (float*)(ws + O_kq);
    float* nq2  = (float*)(ws + O_nq2);
    float* nk2  = (float*)(ws + O_nk2);
    float* A    = (float*)(ws + O_A);
    u16*   W3   = (u16*)(ws + O_W3);
    float* b3   = (float*)(ws + O_b3);

    // zero the accumulated buffers (G + ysum + xsum are contiguous)
    hipMemsetAsync(ws + O_G, 0, SZ_G + (size_t)2 * kB * kD * 4, stream);

    ln_kernel<<<2048, 256, 0, stream>>>(input_S, lnS_w, lnS_b, Yt, nullptr, ysum);
    ln_kernel<<<2048, 256, 0, stream>>>(input_R, lnR_w, lnR_b, Xt, Xrow, xsum);
    gram_kernel<<<768, 256, 0, stream>>>(Yt, Xt, G);
    tmul_kernel<<<384, 256, 0, stream>>>(G, Wq, Wkv, T);
    vec_kernel<<<4, 256, 0, stream>>>(T, Wq, Wkv, bq, bkv, ysum, xsum, qy, kq, nq2, nk2);
    attn_kernel<<<1024, 128, 0, stream>>>(T, Wkv, bq, bkv, qy, kq, nq2, nk2, temp, A);
    mmat_kernel<<<1024, 256, 0, stream>>>(A, Wo, Wkv, bkv, bo, W3, b3);
    outgemm_kernel<<<2048, 256, 0, stream>>>(Xrow, W3, b3, out);
}

// Round 4
// 440.820 us; speedup vs baseline: 1.1597x; 1.1597x over previous
//
#include <hip/hip_runtime.h>
#include <hip/hip_bf16.h>

typedef __attribute__((ext_vector_type(8))) short short8;
typedef __attribute__((ext_vector_type(4))) float f32x4;
typedef unsigned short u16;

#define DEVI static __device__ __forceinline__

constexpr int kB = 4;
constexpr int kN = 16384;
constexpr int kD = 256;
constexpr int kH = 2;
constexpr int kC = 128;

// ---------------- workspace layout (bytes) ----------------
constexpr size_t SZ_T16 = (size_t)kB * kD * kN * 2;   // one bf16 [4][256][16384] buffer
constexpr size_t O_Yt   = 0;                          // bf16 [4][256][16384]  LN(S) transposed
constexpr size_t O_Xt   = O_Yt + SZ_T16;              // bf16 [4][256][16384]  LN(R) transposed
constexpr size_t O_Xrow = O_Xt + SZ_T16;              // bf16 [4][16384][256]  LN(R) row-major
constexpr size_t SZ_G   = (size_t)3 * kB * kD * kD * 4;
constexpr size_t O_G    = O_Xrow + SZ_T16;            // f32 [3][4][256][256]  Gyx,Gyy,Gxx
constexpr size_t O_ysum = O_G + SZ_G;                 // f32 [4][256]
constexpr size_t O_xsum = O_ysum + (size_t)kB * kD * 4;
constexpr size_t O_T    = O_xsum + (size_t)kB * kD * 4; // f32 [3][4][256][256] T1,T2,T3
constexpr size_t O_qy   = O_T + SZ_G;                 // f32 [4][256]
constexpr size_t O_kq   = O_qy + (size_t)kB * kD * 4;
constexpr size_t O_nq2  = O_kq + (size_t)kB * kD * 4;
constexpr size_t O_nk2  = O_nq2 + (size_t)kB * kD * 4;
constexpr size_t O_A    = O_nk2 + (size_t)kB * kD * 4; // f32 [4][2][128][128]
constexpr size_t SZ_A   = (size_t)kB * kH * kC * kC * 4;
constexpr size_t O_W3   = O_A + SZ_A;                 // bf16 [4][256][256]
constexpr size_t O_b3   = O_W3 + (size_t)kB * kD * kD * 2; // f32 [4][256]
constexpr size_t WS_NEED = O_b3 + (size_t)kB * kD * 4;    // ~109 MB

DEVI u16 f2bf(float x) {
    unsigned u = __builtin_bit_cast(unsigned, x);
    unsigned r = (u + 0x7FFFu + ((u >> 16) & 1u)) >> 16;
    return (u16)r;
}

// async global->LDS, 16B per lane; lds ptr must be wave-uniform (HW adds lane*16)
DEVI void gload_lds16(const void* g, void* l) {
    __builtin_amdgcn_global_load_lds(
        (const __attribute__((address_space(1))) unsigned int*)g,
        (__attribute__((address_space(3))) unsigned int*)l, 16, 0, 0);
}

// ---------------- 1) LayerNorm: f32 [b][n][256] -> bf16 transposed [b][256][n]
//                    (+ optional row-major bf16 copy, + per-(b,col) sums) ------
__global__ __launch_bounds__(256) void ln_kernel(
    const float* __restrict__ x, const float* __restrict__ w, const float* __restrict__ bia,
    u16* __restrict__ outT, u16* __restrict__ outR, float* __restrict__ colsum)
{
    constexpr int ROWS = 32;
    __shared__ u16 tile[256][36];     // stride 36 u16 = 72B (bank decorrelation)
    __shared__ float csum[4][256];
    int blk = blockIdx.x;
    int b = blk >> 9;                 // 512 blocks per b
    int n0 = (blk & 511) * ROWS;
    int lane = threadIdx.x & 63, wave = threadIdx.x >> 6;

    float wv[4], bv[4];
#pragma unroll
    for (int j = 0; j < 4; j++) { int c = lane + 64 * j; wv[j] = w[c]; bv[j] = bia[c]; }
    float acc[4] = {0.f, 0.f, 0.f, 0.f};

    for (int i = 0; i < 8; i++) {
        int r = wave * 8 + i;
        const float* xp = x + ((size_t)(b * kN + n0 + r)) * kD;
        float v[4];
#pragma unroll
        for (int j = 0; j < 4; j++) v[j] = xp[lane + 64 * j];
        float s  = v[0] + v[1] + v[2] + v[3];
        float sq = v[0]*v[0] + v[1]*v[1] + v[2]*v[2] + v[3]*v[3];
#pragma unroll
        for (int off = 32; off; off >>= 1) { s += __shfl_xor(s, off); sq += __shfl_xor(sq, off); }
        float mean = s * (1.f / kD);
        float var  = sq * (1.f / kD) - mean * mean;   // biased, matches jnp.var
        float rstd = rsqrtf(var + 1e-5f);
#pragma unroll
        for (int j = 0; j < 4; j++) {
            float y = (v[j] - mean) * rstd * wv[j] + bv[j];
            acc[j] += y;
            u16 u = f2bf(y);
            tile[lane + 64 * j][r] = u;
            if (outR) outR[((size_t)(b * kN + n0 + r)) * kD + lane + 64 * j] = u;
        }
    }
#pragma unroll
    for (int j = 0; j < 4; j++) csum[wave][lane + 64 * j] = acc[j];
    __syncthreads();
    int t = threadIdx.x;
    unsafeAtomicAdd(&colsum[b * kD + t], csum[0][t] + csum[1][t] + csum[2][t] + csum[3][t]);

    // transposed write-out: each (c) row emits 32 contiguous n as 2x16B
#pragma unroll
    for (int pass = 0; pass < 2; pass++) {
        int c = pass * 128 + (t >> 1);
        int q = t & 1;
        const u16* src = &tile[c][q * 16];
        uint2 p0 = *(const uint2*)(src + 0);
        uint2 p1 = *(const uint2*)(src + 4);
        uint2 p2 = *(const uint2*)(src + 8);
        uint2 p3 = *(const uint2*)(src + 12);
        u16* dst = outT + ((size_t)(b * kD + c)) * kN + n0 + q * 16;
        *(uint4*)(dst)     = make_uint4(p0.x, p0.y, p1.x, p1.y);
        *(uint4*)(dst + 8) = make_uint4(p2.x, p2.y, p3.x, p3.y);
    }
}

// ---------------- 2) Gram kernel: m97-style LDS-staged MFMA, split-K atomics ----
// Single LDS block: A tile at [0,16384), B tile at [16384,32768) — manual offsets
// (two separate __shared__ arrays have UNSPECIFIED relative placement).
// LDS [128][64] bf16 linear dest; global source pre-swizzled (slot ^= row&7);
// ds_read applies the same involution -> bank-spread, data consistent.
__global__ __launch_bounds__(256) void gram_kernel(
    const u16* __restrict__ Yt, const u16* __restrict__ Xt, float* __restrict__ G)
{
    __shared__ __align__(16) char smem[32768];

    int id = blockIdx.x;            // 4b * 16chunk * 3which * 4tile = 768
    int b = id / 192;
    int r = id % 192;
    int chunk = r / 12;
    int r2 = r % 12;
    int which = r2 >> 2;            // 0:Gyx 1:Gyy 2:Gxx
    int tm = (r2 >> 1) & 1, tn = r2 & 1;
    const u16* Ap = (which == 2) ? Xt : Yt;
    const u16* Bp = (which == 1) ? Yt : Xt;

    int lane = threadIdx.x & 63, wave = threadIdx.x >> 6;
    int wr = wave >> 1, wc = wave & 1;
    int li = lane & 15, klo = lane >> 4;

    // staging source: unit u covers (row=u>>3, slot=u&7); pre-swizzle slot by row&7
    const u16* Abase = Ap + ((size_t)(b * kD + tm * 128)) * kN + (size_t)chunk * 1024;
    const u16* Bbase = Bp + ((size_t)(b * kD + tn * 128)) * kN + (size_t)chunk * 1024;
    const u16* gsrcA[4];
    const u16* gsrcB[4];
    char* ldst[4];
#pragma unroll
    for (int j = 0; j < 4; j++) {
        int u = (wave * 4 + j) * 64 + lane;
        int row = u >> 3;
        int sl = ((u & 7) ^ (row & 7)) * 8;          // element offset within row
        gsrcA[j] = Abase + (size_t)row * kN + sl;
        gsrcB[j] = Bbase + (size_t)row * kN + sl;
        ldst[j] = smem + (wave * 4 + j) * 1024;       // A at +0, B at +16384
    }

    // LDS read offsets (bytes), step-invariant: frag row, col = kk*32+klo*8 elems, swizzled
    unsigned offA[2][4], offB[2][4];
#pragma unroll
    for (int kk = 0; kk < 2; kk++)
#pragma unroll
        for (int f = 0; f < 4; f++) {
            int rowA = wr * 64 + f * 16 + li;
            int rowB = wc * 64 + f * 16 + li;
            int e = kk * 32 + klo * 8;
            offA[kk][f] = rowA * 128 + ((e ^ ((rowA & 7) << 3)) * 2);
            offB[kk][f] = 16384 + rowB * 128 + ((e ^ ((rowB & 7) << 3)) * 2);
        }

    f32x4 acc[4][4] = {};
    for (int step = 0; step < 16; step++) {
#pragma unroll
        for (int j = 0; j < 4; j++) {
            gload_lds16(gsrcA[j] + step * 64, ldst[j]);
            gload_lds16(gsrcB[j] + step * 64, ldst[j] + 16384);
        }
        __syncthreads();
#pragma unroll
        for (int kk = 0; kk < 2; kk++) {
            short8 a[4], bb[4];
#pragma unroll
            for (int f = 0; f < 4; f++) a[f]  = *(const short8*)(smem + offA[kk][f]);
#pragma unroll
            for (int f = 0; f < 4; f++) bb[f] = *(const short8*)(smem + offB[kk][f]);
#pragma unroll
            for (int fi = 0; fi < 4; fi++)
#pragma unroll
                for (int fj = 0; fj < 4; fj++)
                    acc[fi][fj] = __builtin_amdgcn_mfma_f32_16x16x32_bf16(a[fi], bb[fj], acc[fi][fj], 0, 0, 0);
        }
        __syncthreads();
    }

    float* Gb = G + ((size_t)(which * 4 + b)) * (kD * kD);
#pragma unroll
    for (int fi = 0; fi < 4; fi++) {
        int row = tm * 128 + wr * 64 + fi * 16 + klo * 4;
#pragma unroll
        for (int fj = 0; fj < 4; fj++) {
            int col = tn * 128 + wc * 64 + fj * 16 + li;
#pragma unroll
            for (int rr = 0; rr < 4; rr++)
                unsafeAtomicAdd(&Gb[(size_t)(row + rr) * kD + col], acc[fi][fj][rr]);
        }
    }
}

// ---------------- 3) T{1,2,3}[w][b] = Wrow * G[w][b] ----------------
__global__ __launch_bounds__(256) void tmul_kernel(
    const float* __restrict__ G, const float* __restrict__ Wq, const float* __restrict__ Wkv,
    float* __restrict__ T)
{
    int id = blockIdx.x;            // 3*4*32 = 384
    int otile = id & 31; id >>= 5;
    int b = id & 3;      id >>= 2;
    int which = id;                  // 0:Wq*Gyx 1:Wq*Gyy 2:Wk*Gxx
    const float* W  = (which == 2) ? Wkv : Wq;
    const float* Gb = G + ((size_t)(which * 4 + b)) * (kD * kD);
    float* Tb       = T + ((size_t)(which * 4 + b)) * (kD * kD);
    int d = threadIdx.x;
    int o0 = otile * 8;
    float acc[8] = {};
    for (int m = 0; m < 256; m++) {
        float g = Gb[(size_t)m * kD + d];
#pragma unroll
        for (int oo = 0; oo < 8; oo++) acc[oo] = fmaf(W[(o0 + oo) * kD + m], g, acc[oo]);
    }
#pragma unroll
    for (int oo = 0; oo < 8; oo++) Tb[(size_t)(o0 + oo) * kD + d] = acc[oo];
}

// ---------------- 4) per-channel scalars: qy,kq,|q|^2,|k|^2 ----------------
__global__ __launch_bounds__(256) void vec_kernel(
    const float* __restrict__ T, const float* __restrict__ Wq, const float* __restrict__ Wkv,
    const float* __restrict__ bq, const float* __restrict__ bkv,
    const float* __restrict__ ysum, const float* __restrict__ xsum,
    float* __restrict__ qy, float* __restrict__ kq,
    float* __restrict__ nq2, float* __restrict__ nk2)
{
    __shared__ float ys[256], xs[256];
    int b = blockIdx.x, e = threadIdx.x;
    ys[e] = ysum[b * kD + e];
    xs[e] = xsum[b * kD + e];
    __syncthreads();
    const float* T2  = T + ((size_t)(1 * 4 + b)) * (kD * kD) + (size_t)e * kD;
    const float* T3  = T + ((size_t)(2 * 4 + b)) * (kD * kD) + (size_t)e * kD;
    const float* wqr = Wq + (size_t)e * kD;
    const float* wkr = Wkv + (size_t)e * kD;
    float dqy = 0, dkq = 0, d2 = 0, d3 = 0;
    for (int m = 0; m < 256; m++) {
        float a = wqr[m], c = wkr[m];
        dqy = fmaf(a, ys[m], dqy);
        dkq = fmaf(c, xs[m], dkq);
        d2  = fmaf(T2[m], a, d2);
        d3  = fmaf(T3[m], c, d3);
    }
    float bqe = bq[e], bke = bkv[e];
    qy[b * kD + e] = dqy;
    kq[b * kD + e] = dkq;
    nq2[b * kD + e] = d2 + 2.f * bqe * dqy + (float)kN * bqe * bqe;
    nk2[b * kD + e] = d3 + 2.f * bke * dkq + (float)kN * bke * bke;
}

// ---------------- 5) logits + softmax -> A[b][h][c][d] ----------------
__global__ __launch_bounds__(128) void attn_kernel(
    const float* __restrict__ T, const float* __restrict__ Wkv,
    const float* __restrict__ bq, const float* __restrict__ bkv,
    const float* __restrict__ qy, const float* __restrict__ kq,
    const float* __restrict__ nq2, const float* __restrict__ nk2,
    const float* __restrict__ temperature, float* __restrict__ A)
{
    __shared__ float t1[256];
    __shared__ float red[4];
    int id = blockIdx.x;            // 4*2*128 = 1024, c fastest
    int c = id & 127; id >>= 7;
    int h = id & 1;
    int b = id >> 1;
    int e = h * 128 + c;
    int d = threadIdx.x;

    const float* T1 = T + ((size_t)(0 * 4 + b)) * (kD * kD) + (size_t)e * kD;
    t1[d] = T1[d];
    t1[128 + d] = T1[128 + d];
    __syncthreads();

    int f = h * 128 + d;
    const float* wkr = Wkv + (size_t)f * kD;
    float acc = 0;
    for (int m = 0; m < 256; m++) acc = fmaf(t1[m], wkr[m], acc);

    float bqe = bq[e], bkf = bkv[f];
    float graw = acc + bqe * kq[b * kD + f] + bkf * qy[b * kD + e] + (float)kN * bqe * bkf;
    float rq = 1.f / fmaxf(sqrtf(fmaxf(nq2[b * kD + e], 0.f)), 1e-12f);
    float rk = 1.f / fmaxf(sqrtf(fmaxf(nk2[b * kD + f], 0.f)), 1e-12f);
    float logit = graw * rq * rk * temperature[h];

    float mx = logit;
#pragma unroll
    for (int off = 32; off; off >>= 1) mx = fmaxf(mx, __shfl_xor(mx, off));
    int wv = d >> 6;
    if ((d & 63) == 0) red[wv] = mx;
    __syncthreads();
    mx = fmaxf(red[0], red[1]);
    float p = __expf(logit - mx);
    float sm = p;
#pragma unroll
    for (int off = 32; off; off >>= 1) sm += __shfl_xor(sm, off);
    if ((d & 63) == 0) red[2 + wv] = sm;
    __syncthreads();
    sm = red[2] + red[3];
    A[((size_t)((b * 2 + h) * kC + c)) * kC + d] = p / sm;
}

// ---------------- 6) fold Wo * blockdiag(A) * Wv -> W3[b] (bf16), b3[b] ----------------
__global__ __launch_bounds__(256) void mmat_kernel(
    const float* __restrict__ A, const float* __restrict__ Wo,
    const float* __restrict__ Wkv, const float* __restrict__ bkv,
    const float* __restrict__ bo, u16* __restrict__ W3, float* __restrict__ b3)
{
    __shared__ float Ml[256];
    int id = blockIdx.x;            // 4*256 = 1024
    int o = id & 255;
    int b = id >> 8;
    int t = threadIdx.x;
    int h = t >> 7, d = t & 127;

    const float* Ab  = A + ((size_t)(b * 2 + h)) * (kC * kC);
    const float* wor = Wo + (size_t)o * kD + h * 128;
    float acc = 0;
    for (int c2 = 0; c2 < 128; c2++) acc = fmaf(wor[c2], Ab[(size_t)c2 * kC + d], acc);
    Ml[t] = acc;
    __syncthreads();

    const float* wvp = Wkv + (size_t)256 * kD;   // rows 256..511 = Wv
    float w3 = 0, bsum = 0;
    for (int e2 = 0; e2 < 256; e2++) {
        float m = Ml[e2];
        w3   = fmaf(m, wvp[(size_t)e2 * kD + t], w3);
        bsum = fmaf(m, bkv[256 + e2], bsum);
    }
    W3[((size_t)(b * kD + o)) * kD + t] = f2bf(w3);
    if (t == 0) b3[b * kD + o] = bsum + bo[o];
}

// ---------------- 7) outgemm (m97-style): out[b][n][o] = Xrow . W3^T + b3 ----------------
__global__ __launch_bounds__(256) void outgemm_kernel(
    const u16* __restrict__ Xrow, const u16* __restrict__ W3,
    const float* __restrict__ b3, float* __restrict__ out)
{
    __shared__ __align__(16) char smem[32768];

    int id = blockIdx.x;            // 4b * 128mtile * 2ntile = 1024
    int ntile = id & 1;  id >>= 1;
    int mtile = id & 127; id >>= 7;
    int b = id;
    int lane = threadIdx.x & 63, wave = threadIdx.x >> 6;
    int wr = wave >> 1, wc = wave & 1;
    int li = lane & 15, klo = lane >> 4;

    const u16* Abase = Xrow + ((size_t)(b * kN + mtile * 128)) * kD;
    const u16* Bbase = W3 + ((size_t)(b * kD + ntile * 128)) * kD;
    const u16* gsrcA[4];
    const u16* gsrcB[4];
    char* ldst[4];
#pragma unroll
    for (int j = 0; j < 4; j++) {
        int u = (wave * 4 + j) * 64 + lane;
        int row = u >> 3;
        int sl = ((u & 7) ^ (row & 7)) * 8;
        gsrcA[j] = Abase + (size_t)row * kD + sl;
        gsrcB[j] = Bbase + (size_t)row * kD + sl;
        ldst[j] = smem + (wave * 4 + j) * 1024;
    }
    unsigned offA[2][4], offB[2][4];
#pragma unroll
    for (int kk = 0; kk < 2; kk++)
#pragma unroll
        for (int f = 0; f < 4; f++) {
            int rowA = wr * 64 + f * 16 + li;
            int rowB = wc * 64 + f * 16 + li;
            int e = kk * 32 + klo * 8;
            offA[kk][f] = rowA * 128 + ((e ^ ((rowA & 7) << 3)) * 2);
            offB[kk][f] = 16384 + rowB * 128 + ((e ^ ((rowB & 7) << 3)) * 2);
        }

    f32x4 acc[4][4] = {};
    for (int step = 0; step < 4; step++) {
#pragma unroll
        for (int j = 0; j < 4; j++) {
            gload_lds16(gsrcA[j] + step * 64, ldst[j]);
            gload_lds16(gsrcB[j] + step * 64, ldst[j] + 16384);
        }
        __syncthreads();
#pragma unroll
        for (int kk = 0; kk < 2; kk++) {
            short8 a[4], bb[4];
#pragma unroll
            for (int f = 0; f < 4; f++) a[f]  = *(const short8*)(smem + offA[kk][f]);
#pragma unroll
            for (int f = 0; f < 4; f++) bb[f] = *(const short8*)(smem + offB[kk][f]);
#pragma unroll
            for (int fi = 0; fi < 4; fi++)
#pragma unroll
                for (int fj = 0; fj < 4; fj++)
                    acc[fi][fj] = __builtin_amdgcn_mfma_f32_16x16x32_bf16(a[fi], bb[fj], acc[fi][fj], 0, 0, 0);
        }
        __syncthreads();
    }

    int n0 = mtile * 128 + wr * 64;
    int o0 = ntile * 128 + wc * 64;
#pragma unroll
    for (int fj = 0; fj < 4; fj++) {
        float bias = b3[b * kD + o0 + fj * 16 + li];
#pragma unroll
        for (int fi = 0; fi < 4; fi++) {
            int nr = n0 + fi * 16 + klo * 4;
#pragma unroll
            for (int rr = 0; rr < 4; rr++)
                out[((size_t)(b * kN + nr + rr)) * kD + o0 + fj * 16 + li] = acc[fi][fj][rr] + bias;
        }
    }
}

// ---------------- launch ----------------
extern "C" void kernel_launch(void* const* d_in, const int* in_sizes, int n_in,
                              void* d_out, int out_size, void* d_ws, size_t ws_size,
                              hipStream_t stream)
{
    const float* input_R = (const float*)d_in[0];
    const float* input_S = (const float*)d_in[1];
    const float* lnS_w   = (const float*)d_in[2];
    const float* lnS_b   = (const float*)d_in[3];
    const float* lnR_w   = (const float*)d_in[4];
    const float* lnR_b   = (const float*)d_in[5];
    const float* Wq      = (const float*)d_in[6];
    const float* bq      = (const float*)d_in[7];
    const float* Wkv     = (const float*)d_in[8];
    const float* bkv     = (const float*)d_in[9];
    const float* Wo      = (const float*)d_in[10];
    const float* bo      = (const float*)d_in[11];
    const float* temp    = (const float*)d_in[12];
    float* out = (float*)d_out;
    char* ws = (char*)d_ws;

    u16*   Yt   = (u16*)(ws + O_Yt);
    u16*   Xt   = (u16*)(ws + O_Xt);
    u16*   Xrow = (u16*)(ws + O_Xrow);
    float* G    = (float*)(ws + O_G);
    float* ysum = (float*)(ws + O_ysum);
    float* xsum = (float*)(ws + O_xsum);
    float* T    = (float*)(ws + O_T);
    float* qy   = (float*)(ws + O_qy);
    float* kq   = (float*)(ws + O_kq);
    float* nq2  = (float*)(ws + O_nq2);
    float* nk2  = (float*)(ws + O_nk2);
    float* A    = (float*)(ws + O_A);
    u16*   W3   = (u16*)(ws + O_W3);
    float* b3   = (float*)(ws + O_b3);

    // zero the accumulated buffers (G + ysum + xsum are contiguous)
    hipMemsetAsync(ws + O_G, 0, SZ_G + (size_t)2 * kB * kD * 4, stream);

    ln_kernel<<<2048, 256, 0, stream>>>(input_S, lnS_w, lnS_b, Yt, nullptr, ysum);
    ln_kernel<<<2048, 256, 0, stream>>>(input_R, lnR_w, lnR_b, Xt, Xrow, xsum);
    gram_kernel<<<768, 256, 0, stream>>>(Yt, Xt, G);
    tmul_kernel<<<384, 256, 0, stream>>>(G, Wq, Wkv, T);
    vec_kernel<<<4, 256, 0, stream>>>(T, Wq, Wkv, bq, bkv, ysum, xsum, qy, kq, nq2, nk2);
    attn_kernel<<<1024, 128, 0, stream>>>(T, Wkv, bq, bkv, qy, kq, nq2, nk2, temp, A);
    mmat_kernel<<<1024, 256, 0, stream>>>(A, Wo, Wkv, bkv, bo, W3, b3);
    outgemm_kernel<<<1024, 256, 0, stream>>>(Xrow, W3, b3, out);
}

// Round 5
// 399.995 us; speedup vs baseline: 1.2781x; 1.1021x over previous
//
#include <hip/hip_runtime.h>
#include <hip/hip_bf16.h>

typedef __attribute__((ext_vector_type(8))) short short8;
typedef __attribute__((ext_vector_type(4))) float f32x4;
typedef unsigned short u16;

#define DEVI static __device__ __forceinline__

constexpr int kB = 4;
constexpr int kN = 16384;
constexpr int kD = 256;
constexpr int kH = 2;
constexpr int kC = 128;

// ---------------- workspace layout (bytes) ----------------
constexpr size_t SZ_T16 = (size_t)kB * kD * kN * 2;   // one bf16 [4][256][16384] buffer
constexpr size_t O_Yt   = 0;                          // bf16 [4][256][16384]  LN(S) transposed
constexpr size_t O_Xt   = O_Yt + SZ_T16;              // bf16 [4][256][16384]  LN(R) transposed
constexpr size_t O_Xrow = O_Xt + SZ_T16;              // bf16 [4][16384][256]  LN(R) row-major
constexpr size_t SZ_G   = (size_t)3 * kB * kD * kD * 4;
constexpr size_t O_G    = O_Xrow + SZ_T16;            // f32 [3][4][256][256]  Gyx,Gyy,Gxx
constexpr size_t O_ysum = O_G + SZ_G;                 // f32 [4][256]
constexpr size_t O_xsum = O_ysum + (size_t)kB * kD * 4;
constexpr size_t O_T    = O_xsum + (size_t)kB * kD * 4; // f32 [3][4][256][256] T1,T2,T3
constexpr size_t O_qy   = O_T + SZ_G;                 // f32 [4][256]
constexpr size_t O_kq   = O_qy + (size_t)kB * kD * 4;
constexpr size_t O_nq2  = O_kq + (size_t)kB * kD * 4;
constexpr size_t O_nk2  = O_nq2 + (size_t)kB * kD * 4;
constexpr size_t O_A    = O_nk2 + (size_t)kB * kD * 4; // f32 [4][2][128][128]
constexpr size_t SZ_A   = (size_t)kB * kH * kC * kC * 4;
constexpr size_t O_W3   = O_A + SZ_A;                 // bf16 [4][256][256]
constexpr size_t O_b3   = O_W3 + (size_t)kB * kD * kD * 2; // f32 [4][256]
constexpr size_t WS_NEED = O_b3 + (size_t)kB * kD * 4;    // ~109 MB

DEVI u16 f2bf(float x) {
    unsigned u = __builtin_bit_cast(unsigned, x);
    unsigned r = (u + 0x7FFFu + ((u >> 16) & 1u)) >> 16;
    return (u16)r;
}

// async global->LDS, 16B per lane; lds ptr must be wave-uniform (HW adds lane*16)
DEVI void gload_lds16(const void* g, void* l) {
    __builtin_amdgcn_global_load_lds(
        (const __attribute__((address_space(1))) unsigned int*)g,
        (__attribute__((address_space(3))) unsigned int*)l, 16, 0, 0);
}

// ---------------- 1) LayerNorm: f32 [b][n][256] -> bf16 transposed [b][256][n]
//                    (+ optional row-major bf16 copy, + per-(b,col) sums) ------
__global__ __launch_bounds__(256) void ln_kernel(
    const float* __restrict__ x, const float* __restrict__ w, const float* __restrict__ bia,
    u16* __restrict__ outT, u16* __restrict__ outR, float* __restrict__ colsum)
{
    constexpr int ROWS = 32;
    __shared__ u16 tile[256][36];     // stride 36 u16 = 72B (bank decorrelation)
    __shared__ float csum[4][256];
    int blk = blockIdx.x;
    int b = blk >> 9;                 // 512 blocks per b
    int n0 = (blk & 511) * ROWS;
    int lane = threadIdx.x & 63, wave = threadIdx.x >> 6;

    float wv[4], bv[4];
#pragma unroll
    for (int j = 0; j < 4; j++) { int c = lane + 64 * j; wv[j] = w[c]; bv[j] = bia[c]; }
    float acc[4] = {0.f, 0.f, 0.f, 0.f};

    for (int i = 0; i < 8; i++) {
        int r = wave * 8 + i;
        const float* xp = x + ((size_t)(b * kN + n0 + r)) * kD;
        float v[4];
#pragma unroll
        for (int j = 0; j < 4; j++) v[j] = xp[lane + 64 * j];
        float s  = v[0] + v[1] + v[2] + v[3];
        float sq = v[0]*v[0] + v[1]*v[1] + v[2]*v[2] + v[3]*v[3];
#pragma unroll
        for (int off = 32; off; off >>= 1) { s += __shfl_xor(s, off); sq += __shfl_xor(sq, off); }
        float mean = s * (1.f / kD);
        float var  = sq * (1.f / kD) - mean * mean;   // biased, matches jnp.var
        float rstd = rsqrtf(var + 1e-5f);
#pragma unroll
        for (int j = 0; j < 4; j++) {
            float y = (v[j] - mean) * rstd * wv[j] + bv[j];
            acc[j] += y;
            u16 u = f2bf(y);
            tile[lane + 64 * j][r] = u;
            if (outR) outR[((size_t)(b * kN + n0 + r)) * kD + lane + 64 * j] = u;
        }
    }
#pragma unroll
    for (int j = 0; j < 4; j++) csum[wave][lane + 64 * j] = acc[j];
    __syncthreads();
    int t = threadIdx.x;
    unsafeAtomicAdd(&colsum[b * kD + t], csum[0][t] + csum[1][t] + csum[2][t] + csum[3][t]);

    // transposed write-out: each (c) row emits 32 contiguous n as 2x16B
#pragma unroll
    for (int pass = 0; pass < 2; pass++) {
        int c = pass * 128 + (t >> 1);
        int q = t & 1;
        const u16* src = &tile[c][q * 16];
        uint2 p0 = *(const uint2*)(src + 0);
        uint2 p1 = *(const uint2*)(src + 4);
        uint2 p2 = *(const uint2*)(src + 8);
        uint2 p3 = *(const uint2*)(src + 12);
        u16* dst = outT + ((size_t)(b * kD + c)) * kN + n0 + q * 16;
        *(uint4*)(dst)     = make_uint4(p0.x, p0.y, p1.x, p1.y);
        *(uint4*)(dst + 8) = make_uint4(p2.x, p2.y, p3.x, p3.y);
    }
}

// ---------------- 2) Gram kernel: 2-phase double-buffered LDS MFMA, split-K atomics
// Layout: bufA0 [0,16K) bufB0 [16K,32K) bufA1 [32K,48K) bufB1 [48K,64K).
// Per step: issue STAGE(next) BEFORE computing current -> compiler's pre-barrier
// vmcnt(0) drain lands after the MFMA work, hiding load latency (T3 recipe).
// Global source pre-swizzled (slot ^= row&7); ds_read applies same involution.
__global__ __launch_bounds__(256) void gram_kernel(
    const u16* __restrict__ Yt, const u16* __restrict__ Xt, float* __restrict__ G)
{
    __shared__ __align__(16) char smem[65536];

    int id = blockIdx.x;            // 4b * 16chunk * 3which * 4tile = 768
    int b = id / 192;
    int r = id % 192;
    int chunk = r / 12;
    int r2 = r % 12;
    int which = r2 >> 2;            // 0:Gyx 1:Gyy 2:Gxx
    int tm = (r2 >> 1) & 1, tn = r2 & 1;
    const u16* Ap = (which == 2) ? Xt : Yt;
    const u16* Bp = (which == 1) ? Yt : Xt;

    int lane = threadIdx.x & 63, wave = threadIdx.x >> 6;
    int wr = wave >> 1, wc = wave & 1;
    int li = lane & 15, klo = lane >> 4;

    // staging source: unit u covers (row=u>>3, slot=u&7); pre-swizzle slot by row&7
    const u16* Abase = Ap + ((size_t)(b * kD + tm * 128)) * kN + (size_t)chunk * 1024;
    const u16* Bbase = Bp + ((size_t)(b * kD + tn * 128)) * kN + (size_t)chunk * 1024;
    const u16* gsrcA[4];
    const u16* gsrcB[4];
    unsigned lofs[4];
#pragma unroll
    for (int j = 0; j < 4; j++) {
        int u = (wave * 4 + j) * 64 + lane;
        int row = u >> 3;
        int sl = ((u & 7) ^ (row & 7)) * 8;          // element offset within row
        gsrcA[j] = Abase + (size_t)row * kN + sl;
        gsrcB[j] = Bbase + (size_t)row * kN + sl;
        lofs[j] = (wave * 4 + j) * 1024;              // A at +0, B at +16384
    }

    // LDS read offsets (bytes), buffer-invariant: frag row, col = kk*32+klo*8 elems, swizzled
    unsigned offA[2][4], offB[2][4];
#pragma unroll
    for (int kk = 0; kk < 2; kk++)
#pragma unroll
        for (int f = 0; f < 4; f++) {
            int rowA = wr * 64 + f * 16 + li;
            int rowB = wc * 64 + f * 16 + li;
            int e = kk * 32 + klo * 8;
            offA[kk][f] = rowA * 128 + ((e ^ ((rowA & 7) << 3)) * 2);
            offB[kk][f] = 16384 + rowB * 128 + ((e ^ ((rowB & 7) << 3)) * 2);
        }

    f32x4 acc[4][4] = {};

    auto STAGE = [&](int buf, int step) {
#pragma unroll
        for (int j = 0; j < 4; j++) {
            char* l = smem + (buf << 15) + lofs[j];
            gload_lds16(gsrcA[j] + step * 64, l);
            gload_lds16(gsrcB[j] + step * 64, l + 16384);
        }
    };
    auto COMPUTE = [&](int buf) {
        const char* base = smem + (buf << 15);
#pragma unroll
        for (int kk = 0; kk < 2; kk++) {
            short8 a[4], bb[4];
#pragma unroll
            for (int f = 0; f < 4; f++) a[f]  = *(const short8*)(base + offA[kk][f]);
#pragma unroll
            for (int f = 0; f < 4; f++) bb[f] = *(const short8*)(base + offB[kk][f]);
#pragma unroll
            for (int fi = 0; fi < 4; fi++)
#pragma unroll
                for (int fj = 0; fj < 4; fj++)
                    acc[fi][fj] = __builtin_amdgcn_mfma_f32_16x16x32_bf16(a[fi], bb[fj], acc[fi][fj], 0, 0, 0);
        }
    };

    STAGE(0, 0);
    __syncthreads();                 // compiler drains vmcnt(0): buf0 ready
    int cur = 0;
    for (int step = 0; step < 15; step++) {
        STAGE(cur ^ 1, step + 1);    // issue next tile's loads first
        COMPUTE(cur);                // MFMA hides the load latency
        __syncthreads();             // drain: next buf ready, all reads of cur done
        cur ^= 1;
    }
    COMPUTE(cur);                    // last step, no prefetch

    float* Gb = G + ((size_t)(which * 4 + b)) * (kD * kD);
#pragma unroll
    for (int fi = 0; fi < 4; fi++) {
        int row = tm * 128 + wr * 64 + fi * 16 + klo * 4;
#pragma unroll
        for (int fj = 0; fj < 4; fj++) {
            int col = tn * 128 + wc * 64 + fj * 16 + li;
#pragma unroll
            for (int rr = 0; rr < 4; rr++)
                unsafeAtomicAdd(&Gb[(size_t)(row + rr) * kD + col], acc[fi][fj][rr]);
        }
    }
}

// ---------------- 3) T{1,2,3}[w][b] = Wrow * G[w][b] ----------------
__global__ __launch_bounds__(256) void tmul_kernel(
    const float* __restrict__ G, const float* __restrict__ Wq, const float* __restrict__ Wkv,
    float* __restrict__ T)
{
    int id = blockIdx.x;            // 3*4*32 = 384
    int otile = id & 31; id >>= 5;
    int b = id & 3;      id >>= 2;
    int which = id;                  // 0:Wq*Gyx 1:Wq*Gyy 2:Wk*Gxx
    const float* W  = (which == 2) ? Wkv : Wq;
    const float* Gb = G + ((size_t)(which * 4 + b)) * (kD * kD);
    float* Tb       = T + ((size_t)(which * 4 + b)) * (kD * kD);
    int d = threadIdx.x;
    int o0 = otile * 8;
    float acc[8] = {};
    for (int m = 0; m < 256; m++) {
        float g = Gb[(size_t)m * kD + d];
#pragma unroll
        for (int oo = 0; oo < 8; oo++) acc[oo] = fmaf(W[(o0 + oo) * kD + m], g, acc[oo]);
    }
#pragma unroll
    for (int oo = 0; oo < 8; oo++) Tb[(size_t)(o0 + oo) * kD + d] = acc[oo];
}

// ---------------- 4) per-channel scalars: qy,kq,|q|^2,|k|^2 (16 threads per e) ----
__global__ __launch_bounds__(256) void vec_kernel(
    const float* __restrict__ T, const float* __restrict__ Wq, const float* __restrict__ Wkv,
    const float* __restrict__ bq, const float* __restrict__ bkv,
    const float* __restrict__ ysum, const float* __restrict__ xsum,
    float* __restrict__ qy, float* __restrict__ kq,
    float* __restrict__ nq2, float* __restrict__ nk2)
{
    __shared__ float ys[256], xs[256];
    int blk = blockIdx.x;            // 4b * 16eg = 64
    int b = blk >> 4, eg = blk & 15;
    int t = threadIdx.x;
    ys[t] = ysum[b * kD + t];
    xs[t] = xsum[b * kD + t];
    __syncthreads();
    int el = t >> 4, ml = t & 15;
    int e = eg * 16 + el;
    const float* T2  = T + ((size_t)(1 * 4 + b)) * (kD * kD) + (size_t)e * kD;
    const float* T3  = T + ((size_t)(2 * 4 + b)) * (kD * kD) + (size_t)e * kD;
    const float* wqr = Wq + (size_t)e * kD;
    const float* wkr = Wkv + (size_t)e * kD;
    float dqy = 0, dkq = 0, d2 = 0, d3 = 0;
#pragma unroll
    for (int i = 0; i < 16; i++) {
        int m = i * 16 + ml;         // consecutive lanes -> consecutive m (coalesced)
        float a = wqr[m], c = wkr[m];
        dqy = fmaf(a, ys[m], dqy);
        dkq = fmaf(c, xs[m], dkq);
        d2  = fmaf(T2[m], a, d2);
        d3  = fmaf(T3[m], c, d3);
    }
#pragma unroll
    for (int off = 8; off; off >>= 1) {
        dqy += __shfl_xor(dqy, off);
        dkq += __shfl_xor(dkq, off);
        d2  += __shfl_xor(d2, off);
        d3  += __shfl_xor(d3, off);
    }
    if (ml == 0) {
        float bqe = bq[e], bke = bkv[e];
        qy[b * kD + e] = dqy;
        kq[b * kD + e] = dkq;
        nq2[b * kD + e] = d2 + 2.f * bqe * dqy + (float)kN * bqe * bqe;
        nk2[b * kD + e] = d3 + 2.f * bke * dkq + (float)kN * bke * bke;
    }
}

// ---------------- 5) logits + softmax -> A[b][h][c][d] ----------------
__global__ __launch_bounds__(128) void attn_kernel(
    const float* __restrict__ T, const float* __restrict__ Wkv,
    const float* __restrict__ bq, const float* __restrict__ bkv,
    const float* __restrict__ qy, const float* __restrict__ kq,
    const float* __restrict__ nq2, const float* __restrict__ nk2,
    const float* __restrict__ temperature, float* __restrict__ A)
{
    __shared__ float t1[256];
    __shared__ float red[4];
    int id = blockIdx.x;            // 4*2*128 = 1024, c fastest
    int c = id & 127; id >>= 7;
    int h = id & 1;
    int b = id >> 1;
    int e = h * 128 + c;
    int d = threadIdx.x;

    const float* T1 = T + ((size_t)(0 * 4 + b)) * (kD * kD) + (size_t)e * kD;
    t1[d] = T1[d];
    t1[128 + d] = T1[128 + d];
    __syncthreads();

    int f = h * 128 + d;
    const float* wkr = Wkv + (size_t)f * kD;
    float acc = 0;
    for (int m = 0; m < 256; m++) acc = fmaf(t1[m], wkr[m], acc);

    float bqe = bq[e], bkf = bkv[f];
    float graw = acc + bqe * kq[b * kD + f] + bkf * qy[b * kD + e] + (float)kN * bqe * bkf;
    float rq = 1.f / fmaxf(sqrtf(fmaxf(nq2[b * kD + e], 0.f)), 1e-12f);
    float rk = 1.f / fmaxf(sqrtf(fmaxf(nk2[b * kD + f], 0.f)), 1e-12f);
    float logit = graw * rq * rk * temperature[h];

    float mx = logit;
#pragma unroll
    for (int off = 32; off; off >>= 1) mx = fmaxf(mx, __shfl_xor(mx, off));
    int wv = d >> 6;
    if ((d & 63) == 0) red[wv] = mx;
    __syncthreads();
    mx = fmaxf(red[0], red[1]);
    float p = __expf(logit - mx);
    float sm = p;
#pragma unroll
    for (int off = 32; off; off >>= 1) sm += __shfl_xor(sm, off);
    if ((d & 63) == 0) red[2 + wv] = sm;
    __syncthreads();
    sm = red[2] + red[3];
    A[((size_t)((b * 2 + h) * kC + c)) * kC + d] = p / sm;
}

// ---------------- 6) fold Wo * blockdiag(A) * Wv -> W3[b] (bf16), b3[b] ----------------
__global__ __launch_bounds__(256) void mmat_kernel(
    const float* __restrict__ A, const float* __restrict__ Wo,
    const float* __restrict__ Wkv, const float* __restrict__ bkv,
    const float* __restrict__ bo, u16* __restrict__ W3, float* __restrict__ b3)
{
    __shared__ float Ml[256];
    int id = blockIdx.x;            // 4*256 = 1024
    int o = id & 255;
    int b = id >> 8;
    int t = threadIdx.x;
    int h = t >> 7, d = t & 127;

    const float* Ab  = A + ((size_t)(b * 2 + h)) * (kC * kC);
    const float* wor = Wo + (size_t)o * kD + h * 128;
    float acc = 0;
    for (int c2 = 0; c2 < 128; c2++) acc = fmaf(wor[c2], Ab[(size_t)c2 * kC + d], acc);
    Ml[t] = acc;
    __syncthreads();

    const float* wvp = Wkv + (size_t)256 * kD;   // rows 256..511 = Wv
    float w3 = 0, bsum = 0;
    for (int e2 = 0; e2 < 256; e2++) {
        float m = Ml[e2];
        w3   = fmaf(m, wvp[(size_t)e2 * kD + t], w3);
        bsum = fmaf(m, bkv[256 + e2], bsum);
    }
    W3[((size_t)(b * kD + o)) * kD + t] = f2bf(w3);
    if (t == 0) b3[b * kD + o] = bsum + bo[o];
}

// ---------------- 7) outgemm: 2-phase dbuf, out[b][n][o] = Xrow . W3^T + b3 ----------------
__global__ __launch_bounds__(256) void outgemm_kernel(
    const u16* __restrict__ Xrow, const u16* __restrict__ W3,
    const float* __restrict__ b3, float* __restrict__ out)
{
    __shared__ __align__(16) char smem[65536];

    int id = blockIdx.x;            // 4b * 128mtile * 2ntile = 1024
    int ntile = id & 1;  id >>= 1;
    int mtile = id & 127; id >>= 7;
    int b = id;
    int lane = threadIdx.x & 63, wave = threadIdx.x >> 6;
    int wr = wave >> 1, wc = wave & 1;
    int li = lane & 15, klo = lane >> 4;

    const u16* Abase = Xrow + ((size_t)(b * kN + mtile * 128)) * kD;
    const u16* Bbase = W3 + ((size_t)(b * kD + ntile * 128)) * kD;
    const u16* gsrcA[4];
    const u16* gsrcB[4];
    unsigned lofs[4];
#pragma unroll
    for (int j = 0; j < 4; j++) {
        int u = (wave * 4 + j) * 64 + lane;
        int row = u >> 3;
        int sl = ((u & 7) ^ (row & 7)) * 8;
        gsrcA[j] = Abase + (size_t)row * kD + sl;
        gsrcB[j] = Bbase + (size_t)row * kD + sl;
        lofs[j] = (wave * 4 + j) * 1024;
    }
    unsigned offA[2][4], offB[2][4];
#pragma unroll
    for (int kk = 0; kk < 2; kk++)
#pragma unroll
        for (int f = 0; f < 4; f++) {
            int rowA = wr * 64 + f * 16 + li;
            int rowB = wc * 64 + f * 16 + li;
            int e = kk * 32 + klo * 8;
            offA[kk][f] = rowA * 128 + ((e ^ ((rowA & 7) << 3)) * 2);
            offB[kk][f] = 16384 + rowB * 128 + ((e ^ ((rowB & 7) << 3)) * 2);
        }

    f32x4 acc[4][4] = {};

    auto STAGE = [&](int buf, int step) {
#pragma unroll
        for (int j = 0; j < 4; j++) {
            char* l = smem + (buf << 15) + lofs[j];
            gload_lds16(gsrcA[j] + step * 64, l);
            gload_lds16(gsrcB[j] + step * 64, l + 16384);
        }
    };
    auto COMPUTE = [&](int buf) {
        const char* base = smem + (buf << 15);
#pragma unroll
        for (int kk = 0; kk < 2; kk++) {
            short8 a[4], bb[4];
#pragma unroll
            for (int f = 0; f < 4; f++) a[f]  = *(const short8*)(base + offA[kk][f]);
#pragma unroll
            for (int f = 0; f < 4; f++) bb[f] = *(const short8*)(base + offB[kk][f]);
#pragma unroll
            for (int fi = 0; fi < 4; fi++)
#pragma unroll
                for (int fj = 0; fj < 4; fj++)
                    acc[fi][fj] = __builtin_amdgcn_mfma_f32_16x16x32_bf16(a[fi], bb[fj], acc[fi][fj], 0, 0, 0);
        }
    };

    STAGE(0, 0);
    __syncthreads();
    int cur = 0;
    for (int step = 0; step < 3; step++) {
        STAGE(cur ^ 1, step + 1);
        COMPUTE(cur);
        __syncthreads();
        cur ^= 1;
    }
    COMPUTE(cur);

    int n0 = mtile * 128 + wr * 64;
    int o0 = ntile * 128 + wc * 64;
#pragma unroll
    for (int fj = 0; fj < 4; fj++) {
        float bias = b3[b * kD + o0 + fj * 16 + li];
#pragma unroll
        for (int fi = 0; fi < 4; fi++) {
            int nr = n0 + fi * 16 + klo * 4;
#pragma unroll
            for (int rr = 0; rr < 4; rr++)
                out[((size_t)(b * kN + nr + rr)) * kD + o0 + fj * 16 + li] = acc[fi][fj][rr] + bias;
        }
    }
}

// ---------------- launch ----------------
extern "C" void kernel_launch(void* const* d_in, const int* in_sizes, int n_in,
                              void* d_out, int out_size, void* d_ws, size_t ws_size,
                              hipStream_t stream)
{
    const float* input_R = (const float*)d_in[0];
    const float* input_S = (const float*)d_in[1];
    const float* lnS_w   = (const float*)d_in[2];
    const float* lnS_b   = (const float*)d_in[3];
    const float* lnR_w   = (const float*)d_in[4];
    const float* lnR_b   = (const float*)d_in[5];
    const float* Wq      = (const float*)d_in[6];
    const float* bq      = (const float*)d_in[7];
    const float* Wkv     = (const float*)d_in[8];
    const float* bkv     = (const float*)d_in[9];
    const float* Wo      = (const float*)d_in[10];
    const float* bo      = (const float*)d_in[11];
    const float* temp    = (const float*)d_in[12];
    float* out = (float*)d_out;
    char* ws = (char*)d_ws;

    u16*   Yt   = (u16*)(ws + O_Yt);
    u16*   Xt   = (u16*)(ws + O_Xt);
    u16*   Xrow = (u16*)(ws + O_Xrow);
    float* G    = (float*)(ws + O_G);
    float* ysum = (float*)(ws + O_ysum);
    float* xsum = (float*)(ws + O_xsum);
    float* T    = (float*)(ws + O_T);
    float* qy   = (float*)(ws + O_qy);
    float* kq   = (float*)(ws + O_kq);
    float* nq2  = (float*)(ws + O_nq2);
    float* nk2  = (float*)(ws + O_nk2);
    float* A    = (float*)(ws + O_A);
    u16*   W3   = (u16*)(ws + O_W3);
    float* b3   = (float*)(ws + O_b3);

    // zero the accumulated buffers (G + ysum + xsum are contiguous)
    hipMemsetAsync(ws + O_G, 0, SZ_G + (size_t)2 * kB * kD * 4, stream);

    ln_kernel<<<2048, 256, 0, stream>>>(input_S, lnS_w, lnS_b, Yt, nullptr, ysum);
    ln_kernel<<<2048, 256, 0, stream>>>(input_R, lnR_w, lnR_b, Xt, Xrow, xsum);
    gram_kernel<<<768, 256, 0, stream>>>(Yt, Xt, G);
    tmul_kernel<<<384, 256, 0, stream>>>(G, Wq, Wkv, T);
    vec_kernel<<<64, 256, 0, stream>>>(T, Wq, Wkv, bq, bkv, ysum, xsum, qy, kq, nq2, nk2);
    attn_kernel<<<1024, 128, 0, stream>>>(T, Wkv, bq, bkv, qy, kq, nq2, nk2, temp, A);
    mmat_kernel<<<1024, 256, 0, stream>>>(A, Wo, Wkv, bkv, bo, W3, b3);
    outgemm_kernel<<<1024, 256, 0, stream>>>(Xrow, W3, b3, out);
}